// Round 1
// baseline (405.079 us; speedup 1.0000x reference)
//
#include <hip/hip_runtime.h>
#include <cstdint>
#include <cstddef>

#define HIDDEN   2880
#define QKV_N    5120      // (64 + 2*8)*64
#define OPROJ_K  4096      // 64*64
#define NTOK     2048
#define WIN      128
#define SM_SCALE 0.125f

typedef _Float16 half8  __attribute__((ext_vector_type(8)));
typedef _Float16 half4v __attribute__((ext_vector_type(4)));
typedef float    f32x4  __attribute__((ext_vector_type(4)));

__device__ __forceinline__ void gload16(const void* g, void* l) {
  // async global->LDS, 16B per lane; LDS dest = wave-uniform base + lane*16
  __builtin_amdgcn_global_load_lds((__attribute__((address_space(1))) void*)g,
                                   (__attribute__((address_space(3))) void*)l,
                                   16, 0, 0);
}

__device__ __forceinline__ _Float16 f2h(float f) { return (_Float16)f; }

// ---------------- RMSNorm: x[2048][2880] fp32 -> f16 normalized*scale ----------------
__global__ __launch_bounds__(256) void rmsnorm_kernel(const float* __restrict__ x,
                                                      const float* __restrict__ scale,
                                                      _Float16* __restrict__ out) {
  int row = blockIdx.x, t = threadIdx.x;
  const float4* xr = (const float4*)(x + (size_t)row * HIDDEN);
  const float4* sc = (const float4*)scale;
  float4 v0 = xr[t];
  float4 v1 = xr[t + 256];
  float4 v2 = (t < 208) ? xr[t + 512] : make_float4(0.f, 0.f, 0.f, 0.f);
  float ss = v0.x*v0.x + v0.y*v0.y + v0.z*v0.z + v0.w*v0.w
           + v1.x*v1.x + v1.y*v1.y + v1.z*v1.z + v1.w*v1.w
           + v2.x*v2.x + v2.y*v2.y + v2.z*v2.z + v2.w*v2.w;
  #pragma unroll
  for (int m = 1; m < 64; m <<= 1) ss += __shfl_xor(ss, m, 64);
  __shared__ float red[4];
  if ((t & 63) == 0) red[t >> 6] = ss;
  __syncthreads();
  float inv = 1.0f / sqrtf((red[0] + red[1] + red[2] + red[3]) * (1.0f / HIDDEN) + 1e-5f);
  _Float16* orow = out + (size_t)row * HIDDEN;
  auto store4 = [&](int c4, const float4& v, const float4& s) {
    half4v h;
    h[0] = f2h(v.x * inv * s.x); h[1] = f2h(v.y * inv * s.y);
    h[2] = f2h(v.z * inv * s.z); h[3] = f2h(v.w * inv * s.w);
    *(half4v*)(orow + (size_t)c4 * 4) = h;
  };
  store4(t, v0, sc[t]);
  store4(t + 256, v1, sc[t + 256]);
  if (t < 208) store4(t + 512, v2, sc[t + 512]);
}

// ------------- cast+transpose: W[K][N] fp32 -> Wt[Npad][K] f16 (rows>=N zeroed) -------------
__global__ __launch_bounds__(256) void cast_transpose_kernel(const float* __restrict__ W,
                                                             _Float16* __restrict__ Wt,
                                                             int K, int N) {
  __shared__ float tile[32][33];
  int n0 = blockIdx.x * 32, k0 = blockIdx.y * 32;
  int t = threadIdx.x;
  #pragma unroll
  for (int p = 0; p < 4; ++p) {
    int e = t + p * 256; int r = e >> 5, cc = e & 31;
    float vv = 0.f;
    if (n0 + cc < N) vv = W[(size_t)(k0 + r) * N + n0 + cc];
    tile[r][cc] = vv;
  }
  __syncthreads();
  #pragma unroll
  for (int p = 0; p < 4; ++p) {
    int e = t + p * 256; int r = e >> 5, cc = e & 31;
    Wt[(size_t)(n0 + r) * K + k0 + cc] = (_Float16)tile[cc][r];
  }
}

// ---------------- f16 MFMA GEMM: C[M][N] = A[M][K] * Bt[N][K]^T + bias (+resid) ----------------
// 128x128 tile, BK=32, 256 thr = 4 waves (2x2), each wave 4x4 tiles of 16x16x32 MFMA.
template <bool HALF_OUT>
__global__ __launch_bounds__(256, 2) void gemm_kernel(const _Float16* __restrict__ A,
                                                      const _Float16* __restrict__ Bt,
                                                      const float* __restrict__ bias,
                                                      const float* __restrict__ resid,
                                                      void* __restrict__ Cout,
                                                      int M, int N, int K) {
  __shared__ _Float16 Alds[128 * 32];
  __shared__ _Float16 Blds[128 * 32];
  int tid = threadIdx.x;
  int wave = tid >> 6, lane = tid & 63;
  int wm = wave >> 1, wn = wave & 1;
  int c = lane & 15, quad = lane >> 4;
  int m0 = blockIdx.y * 128, n0 = blockIdx.x * 128;

  int c0 = wave * 128 + lane;   // 16B chunk ids (this wave: c0, c0+64)
  const _Float16* gA0 = A  + (size_t)(m0 + (c0 >> 2)) * K + (c0 & 3) * 8;
  const _Float16* gA1 = A  + (size_t)(m0 + ((c0 + 64) >> 2)) * K + (c0 & 3) * 8;
  const _Float16* gB0 = Bt + (size_t)(n0 + (c0 >> 2)) * K + (c0 & 3) * 8;
  const _Float16* gB1 = Bt + (size_t)(n0 + ((c0 + 64) >> 2)) * K + (c0 & 3) * 8;
  _Float16* lA0 = Alds + wave * 1024;
  _Float16* lA1 = lA0 + 512;
  _Float16* lB0 = Blds + wave * 1024;
  _Float16* lB1 = lB0 + 512;

  f32x4 acc[4][4] = {};
  int nIter = K >> 5;
  for (int kt = 0; kt < nIter; ++kt) {
    __syncthreads();                 // previous iter's LDS reads done
    gload16(gA0, lA0); gload16(gA1, lA1);
    gload16(gB0, lB0); gload16(gB1, lB1);
    gA0 += 32; gA1 += 32; gB0 += 32; gB1 += 32;
    __syncthreads();                 // vmcnt drained -> tiles visible
    half8 a[4], b[4];
    #pragma unroll
    for (int i = 0; i < 4; ++i)
      a[i] = *(const half8*)&Alds[(wm * 64 + i * 16 + c) * 32 + quad * 8];
    #pragma unroll
    for (int j = 0; j < 4; ++j)
      b[j] = *(const half8*)&Blds[(wn * 64 + j * 16 + c) * 32 + quad * 8];
    #pragma unroll
    for (int i = 0; i < 4; ++i)
      #pragma unroll
      for (int j = 0; j < 4; ++j)
        acc[i][j] = __builtin_amdgcn_mfma_f32_16x16x32_f16(a[i], b[j], acc[i][j], 0, 0, 0);
  }

  // epilogue: C layout col=lane&15, row=quad*4+reg
  #pragma unroll
  for (int i = 0; i < 4; ++i) {
    int row = m0 + wm * 64 + i * 16 + quad * 4;
    #pragma unroll
    for (int j = 0; j < 4; ++j) {
      int col = n0 + wn * 64 + j * 16 + c;
      if (col < N) {
        float bv = bias[col];
        #pragma unroll
        for (int r = 0; r < 4; ++r) {
          float v = acc[i][j][r] + bv;
          if (resid) v += resid[(size_t)(row + r) * N + col];
          if (HALF_OUT) ((_Float16*)Cout)[(size_t)(row + r) * N + col] = f2h(v);
          else          ((float*)Cout)[(size_t)(row + r) * N + col] = v;
        }
      }
    }
  }
}

// ---------------- RoPE (YaRN) + split to q/k/v f16 ----------------
__global__ __launch_bounds__(256) void rope_kernel(const _Float16* __restrict__ qkv,
                                                   _Float16* __restrict__ qh,
                                                   _Float16* __restrict__ kh,
                                                   _Float16* __restrict__ vh) {
  int tok = blockIdx.x, t = threadIdx.x;
  __shared__ float cs[32], sn[32];
  if (t < 32) {
    const double PI = 3.14159265358979323846;
    double i = (double)t;
    double lf = log(150000.0);
    double freq = exp(lf * (i / 32.0));
    double interp = 1.0 / (32.0 * freq);
    double extrap = 1.0 / freq;
    double low  = 32.0 * log(4096.0 / (32.0 * 2.0 * PI)) / lf;
    double high = 32.0 * log(4096.0 / (2.0 * PI)) / lf;
    double ramp = (i - low) / (high - low);
    double mm = 1.0 - fmin(fmax(ramp, 0.0), 1.0);
    double invf = interp * (1.0 - mm) + extrap * mm;
    double ang = (double)tok * invf;
    double conc = 0.1 * log(32.0) + 1.0;
    cs[t] = (float)(cos(ang) * conc);
    sn[t] = (float)(sin(ang) * conc);
  }
  __syncthreads();
  const _Float16* row = qkv + (size_t)tok * QKV_N;
  #pragma unroll
  for (int p = 0; p < 8; ++p) {          // 64 q-heads x 32 pairs
    int pid = t + p * 256;
    int hh = pid >> 5, d = pid & 31;
    float x1 = (float)row[hh * 64 + d], x2 = (float)row[hh * 64 + d + 32];
    float cv = cs[d], sv = sn[d];
    _Float16* dst = qh + ((size_t)tok * 64 + hh) * 64 + d;
    dst[0]  = f2h(x1 * cv - x2 * sv);
    dst[32] = f2h(x2 * cv + x1 * sv);
  }
  {                                      // 8 kv-heads x 32 pairs
    int hh = t >> 5, d = t & 31;
    float x1 = (float)row[4096 + hh * 64 + d], x2 = (float)row[4096 + hh * 64 + d + 32];
    float cv = cs[d], sv = sn[d];
    _Float16* dst = kh + ((size_t)tok * 8 + hh) * 64 + d;
    dst[0]  = f2h(x1 * cv - x2 * sv);
    dst[32] = f2h(x2 * cv + x1 * sv);
  }
  #pragma unroll
  for (int p = 0; p < 2; ++p) {          // v passthrough
    int idx = t + p * 256;
    vh[(size_t)tok * 512 + idx] = row[4608 + idx];
  }
}

// ---------------- sliding-window GQA attention with sink ----------------
// block = (q-tile of 16 tokens) x (kv head). M = 8 qmult * 16 q = 128 rows, 144 keys = 9 n-tiles.
#define TQ 16
__global__ __launch_bounds__(256) void attn_kernel(const _Float16* __restrict__ qh,
                                                   const _Float16* __restrict__ kh,
                                                   const _Float16* __restrict__ vh,
                                                   const float* __restrict__ sink,
                                                   _Float16* __restrict__ attn_out) {
  __shared__ _Float16 Vt[64 * 160];    // [d][key], 20.0 KB, keys 144..159 zero
  __shared__ _Float16 Ps[128 * 160];   // [m][key] f16 probs, 40 KB, cols 144..159 zero
  int qt = blockIdx.x, kvh = blockIdx.y;
  int Q0 = qt * TQ;
  int kmin = (Q0 >= WIN) ? Q0 - WIN : 0;
  int nkv = Q0 + TQ - kmin;            // valid keys (<=144)
  int tid = threadIdx.x;
  int wave = tid >> 6, lane = tid & 63;
  int c = lane & 15, quad = lane >> 4;

  // ---- stage V^T into LDS (zero padding cols) ----
  #pragma unroll
  for (int p = 0; p < 5; ++p) {
    int cc = p * 256 + tid;            // 8 d-chunks x 160 cols = 1280
    int col = cc % 160;
    int d0 = (cc / 160) * 8;
    union { uint4 u4; _Float16 hv[8]; } buf;
    if (col < nkv) buf.u4 = *(const uint4*)(vh + ((size_t)(kmin + col) * 8 + kvh) * 64 + d0);
    else           buf.u4 = make_uint4(0, 0, 0, 0);
    #pragma unroll
    for (int uu = 0; uu < 8; ++uu) Vt[(d0 + uu) * 160 + col] = buf.hv[uu];
  }
  // ---- zero Ps pad columns 144..159 ----
  #pragma unroll
  for (int p = 0; p < 8; ++p) {
    int idx = p * 256 + tid;           // 128 rows x 16 cols
    Ps[(idx >> 4) * 160 + 144 + (idx & 15)] = (_Float16)0.f;
  }

  // ---- Q fragments from global (A-layout: m=lane&15, k=quad*8+j) ----
  half8 aq[2][2];
  #pragma unroll
  for (int i = 0; i < 2; ++i) {
    int qm = wave * 2 + i;
    #pragma unroll
    for (int ks = 0; ks < 2; ++ks)
      aq[i][ks] = *(const half8*)(qh + ((size_t)(Q0 + c) * 64 + kvh * 8 + qm) * 64 + ks * 32 + quad * 8);
  }

  // ---- S = Q K^T via MFMA, B-frags straight from global K ----
  f32x4 sacc[2][9] = {};
  #pragma unroll
  for (int j = 0; j < 9; ++j) {
    #pragma unroll
    for (int ks = 0; ks < 2; ++ks) {
      half8 bk = *(const half8*)(kh + ((size_t)(kmin + j * 16 + c) * 8 + kvh) * 64 + ks * 32 + quad * 8);
      #pragma unroll
      for (int i = 0; i < 2; ++i)
        sacc[i][j] = __builtin_amdgcn_mfma_f32_16x16x32_f16(aq[i][ks], bk, sacc[i][j], 0, 0, 0);
    }
  }

  // ---- in-register softmax (C layout: col=lane&15=key, row=quad*4+r=q) + sink ----
  #pragma unroll
  for (int i = 0; i < 2; ++i) {
    int qm = wave * 2 + i;
    float sk = sink[kvh * 8 + qm];
    #pragma unroll
    for (int r = 0; r < 4; ++r) {
      int qpos = Q0 + quad * 4 + r;
      float sv[9]; float mx = -3e38f;
      #pragma unroll
      for (int j = 0; j < 9; ++j) {
        int key = kmin + j * 16 + c;
        float s = sacc[i][j][r] * SM_SCALE;
        bool valid = (key <= qpos) && (qpos - key <= WIN);
        sv[j] = valid ? s : -3e38f;
        mx = fmaxf(mx, sv[j]);
      }
      #pragma unroll
      for (int msk = 1; msk < 16; msk <<= 1) mx = fmaxf(mx, __shfl_xor(mx, msk, 64));
      mx = fmaxf(mx, sk);
      float sum = 0.f; float pv[9];
      #pragma unroll
      for (int j = 0; j < 9; ++j) { float p = __expf(sv[j] - mx); pv[j] = p; sum += p; }
      #pragma unroll
      for (int msk = 1; msk < 16; msk <<= 1) sum += __shfl_xor(sum, msk, 64);
      sum += __expf(sk - mx);
      float inv = 1.0f / sum;
      int mrow = qm * 16 + quad * 4 + r;
      #pragma unroll
      for (int j = 0; j < 9; ++j)
        Ps[mrow * 160 + j * 16 + c] = f2h(pv[j] * inv);
    }
  }

  __syncthreads();   // Vt + Ps pads + P visible to all waves

  // ---- O = P V via MFMA (5 k-steps of 32 keys, tail zero-padded) ----
  f32x4 oacc[2][4] = {};
  #pragma unroll
  for (int ks = 0; ks < 5; ++ks) {
    half8 ap[2], bv[4];
    #pragma unroll
    for (int i = 0; i < 2; ++i)
      ap[i] = *(const half8*)&Ps[((wave * 2 + i) * 16 + c) * 160 + ks * 32 + quad * 8];
    #pragma unroll
    for (int j = 0; j < 4; ++j)
      bv[j] = *(const half8*)&Vt[(j * 16 + c) * 160 + ks * 32 + quad * 8];
    #pragma unroll
    for (int i = 0; i < 2; ++i)
      #pragma unroll
      for (int j = 0; j < 4; ++j)
        oacc[i][j] = __builtin_amdgcn_mfma_f32_16x16x32_f16(ap[i], bv[j], oacc[i][j], 0, 0, 0);
  }

  #pragma unroll
  for (int i = 0; i < 2; ++i) {
    int qm = wave * 2 + i;
    #pragma unroll
    for (int j = 0; j < 4; ++j)
      #pragma unroll
      for (int r = 0; r < 4; ++r) {
        int token = Q0 + quad * 4 + r;
        attn_out[(size_t)token * 4096 + (kvh * 8 + qm) * 64 + j * 16 + c] = f2h(oacc[i][j][r]);
      }
  }
}

// ---------------- launch ----------------
extern "C" void kernel_launch(void* const* d_in, const int* in_sizes, int n_in,
                              void* d_out, int out_size, void* d_ws, size_t ws_size,
                              hipStream_t stream) {
  (void)in_sizes; (void)n_in; (void)out_size; (void)ws_size;
  const float* x      = (const float*)d_in[0];
  const float* scale  = (const float*)d_in[1];
  const float* sink   = (const float*)d_in[2];
  const float* w_qkv  = (const float*)d_in[3];
  const float* b_qkv  = (const float*)d_in[4];
  const float* w_o    = (const float*)d_in[5];
  const float* b_o    = (const float*)d_in[6];
  float* out = (float*)d_out;

  char* ws = (char*)d_ws;
  size_t off = 0;
  auto alloc = [&](size_t bytes) { void* p = ws + off; off += (bytes + 255) & ~(size_t)255; return p; };
  _Float16* a_h   = (_Float16*)alloc((size_t)NTOK * HIDDEN * 2);   // 11.8 MB
  _Float16* wtq   = (_Float16*)alloc((size_t)QKV_N * HIDDEN * 2);  // 29.5 MB  [N][K]
  _Float16* wto   = (_Float16*)alloc((size_t)2944 * OPROJ_K * 2);  // 24.1 MB  [Npad][K]
  _Float16* qkv_h = (_Float16*)alloc((size_t)NTOK * QKV_N * 2);    // 21.0 MB
  _Float16* q_h   = (_Float16*)alloc((size_t)NTOK * 4096 * 2);     // 16.8 MB
  _Float16* k_h   = (_Float16*)alloc((size_t)NTOK * 512 * 2);      //  2.1 MB
  _Float16* v_h   = (_Float16*)alloc((size_t)NTOK * 512 * 2);      //  2.1 MB
  _Float16* at_h  = (_Float16*)alloc((size_t)NTOK * 4096 * 2);     // 16.8 MB  (~124 MB total)

  cast_transpose_kernel<<<dim3(QKV_N / 32, HIDDEN / 32), 256, 0, stream>>>(w_qkv, wtq, HIDDEN, QKV_N);
  cast_transpose_kernel<<<dim3(2944 / 32, OPROJ_K / 32), 256, 0, stream>>>(w_o, wto, OPROJ_K, HIDDEN);
  rmsnorm_kernel<<<NTOK, 256, 0, stream>>>(x, scale, a_h);
  gemm_kernel<true><<<dim3(QKV_N / 128, NTOK / 128), 256, 0, stream>>>(
      a_h, wtq, b_qkv, nullptr, qkv_h, NTOK, QKV_N, HIDDEN);
  rope_kernel<<<NTOK, 256, 0, stream>>>(qkv_h, q_h, k_h, v_h);
  attn_kernel<<<dim3(NTOK / TQ, 8), 256, 0, stream>>>(q_h, k_h, v_h, sink, at_h);
  gemm_kernel<false><<<dim3(23, NTOK / 128), 256, 0, stream>>>(
      at_h, wto, b_o, x, out, NTOK, HIDDEN, OPROJ_K);
}